// Round 10
// baseline (335.039 us; speedup 1.0000x reference)
//
#include <hip/hip_runtime.h>

#define N_Q 8192
#define N_K 16384
#define C_DIM 256
#define BM 256
#define BN 256
#define BK 32
#define NGRAN 256   // 64-code granules
#define GRAN 64
// Rigorous worst-case |d_approx - d_np| <= 1.9e-4; flagging needs 2x = 3.8e-4.
#define MARGIN 4.5e-4f
#define RQS 16           // query-splits per granule in rescore
#define RQB (N_Q / RQS)  // 512 queries per rescore block

typedef __attribute__((ext_vector_type(8))) short short8;
typedef __attribute__((ext_vector_type(4))) float f32x4;
typedef __attribute__((ext_vector_type(4))) unsigned short ushort4_t;
typedef unsigned long long u64;

__device__ inline unsigned short f2bf(float f) {  // RNE fp32->bf16 (finite)
  unsigned u = __float_as_uint(f);
  return (unsigned short)((u + 0x7fffu + ((u >> 16) & 1u)) >> 16);
}

__device__ inline void gl_lds16(const void* g, void* l) {
  __builtin_amdgcn_global_load_lds(
      (const __attribute__((address_space(1))) unsigned int*)g,
      (__attribute__((address_space(3))) unsigned int*)l, 16, 0, 0);
}

// ===========================================================================
// pre_x: 256 blocks x 32-query LDS-tile transpose; exact R1 xsq order
// (4 partials of 64 sequential c, ((p0+p1)+p2)+p3); init packed2.
// ===========================================================================
__global__ __launch_bounds__(256) void vq_pre_x(
    const float* __restrict__ hidden, float* __restrict__ xt,
    unsigned short* __restrict__ xb, float* __restrict__ xsq,
    u64* __restrict__ packed2) {
  __shared__ float xs[C_DIM][36];
  __shared__ float xsq_part[4][32];
  const int tile = blockIdx.x;       // 256 = 8 b x 32 hw-tiles
  const int b = tile >> 5;
  const int hw0 = (tile & 31) * 32;
  const int q0 = b * 1024 + hw0;
  const float* hb = hidden + (size_t)b * (C_DIM * 1024) + hw0;
  const int tid = threadIdx.x;

  for (int idx = tid; idx < C_DIM * 32; idx += 256) {
    int c = idx >> 5, q = idx & 31;
    xs[c][q] = hb[c * 1024 + q];     // coalesced over q
  }
  __syncthreads();

  if (tid < 128) {  // xsq partials, exact R1 c-ranges
    int q = tid & 31, part = tid >> 5, cb0 = part * 64;
    float s = 0.f;
    for (int c = 0; c < 64; ++c) { float v = xs[cb0 + c][q]; s = fmaf(v, v, s); }
    xsq_part[part][q] = s;
  }
  __syncthreads();
  if (tid < 32) {
    xsq[q0 + tid] = ((xsq_part[0][tid] + xsq_part[1][tid]) + xsq_part[2][tid]) +
                    xsq_part[3][tid];
    packed2[q0 + tid] = ~0ull;
  }

  {  // xt + xb row writes: thread -> query tid>>3, 32-c segment (tid&7)*32
    int q = tid >> 3, c0 = (tid & 7) * 32;
    float* xo = xt + (size_t)(q0 + q) * C_DIM + c0;
    unsigned short* bo = xb + (size_t)(q0 + q) * C_DIM + c0;
    for (int i = 0; i < 32; i += 4) {
      float4 v = {xs[c0 + i][q], xs[c0 + i + 1][q], xs[c0 + i + 2][q],
                  xs[c0 + i + 3][q]};
      *reinterpret_cast<float4*>(xo + i) = v;
      ushort4_t bv = {f2bf(v.x), f2bf(v.y), f2bf(v.z), f2bf(v.w)};
      *reinterpret_cast<ushort4_t*>(bo + i) = bv;
    }
  }
}

// ===========================================================================
// pre_e: coalesced staging; exact R1 esq; eb bf16; transposed fp32 ct[c][k].
// ===========================================================================
__global__ __launch_bounds__(256) void vq_pre_e(
    const float* __restrict__ cb, unsigned short* __restrict__ eb,
    float* __restrict__ esq, float* __restrict__ ct) {
  __shared__ float es[64][257];
  const int k0 = blockIdx.x * 64;
  const int tid = threadIdx.x;

  for (int idx = tid; idx < 64 * 64; idx += 256) {
    int kk = idx >> 6, c4 = idx & 63;
    float4 v = reinterpret_cast<const float4*>(cb + (size_t)(k0 + kk) * C_DIM)[c4];
    es[kk][c4 * 4 + 0] = v.x; es[kk][c4 * 4 + 1] = v.y;
    es[kk][c4 * 4 + 2] = v.z; es[kk][c4 * 4 + 3] = v.w;
  }
  __syncthreads();

  if (tid < 64) {  // exact sequential esq chain (R1 order)
    float s = 0.f;
    for (int c = 0; c < 256; ++c) { float v = es[tid][c]; s = fmaf(v, v, s); }
    esq[k0 + tid] = s;
  }

  {  // eb writes coalesced
    int r = tid >> 2, c0 = (tid & 3) * 64;
    unsigned short* bo = eb + (size_t)(k0 + r) * C_DIM + c0;
    for (int i = 0; i < 64; i += 4) {
      ushort4_t bv = {f2bf(es[r][c0 + i]), f2bf(es[r][c0 + i + 1]),
                      f2bf(es[r][c0 + i + 2]), f2bf(es[r][c0 + i + 3])};
      *reinterpret_cast<ushort4_t*>(bo + i) = bv;
    }
  }

  if (ct) {  // transposed write: lanes = rows -> coalesced 256B stores
    const int l = tid & 63, w4 = tid >> 6;
    for (int c = w4; c < C_DIM; c += 4) {
      ct[(size_t)c * N_K + k0 + l] = es[l][c];
    }
  }
}

// ===========================================================================
// Prefilter GEMM v3: 256x256 tile, 8 waves, BK=32 double-buffered -> LDS
// 64KB -> 2 blocks/CU (4 waves/SIMD, 2x R9 occupancy). 2-bit XOR swizzle,
// both-sides: source seg (lane&3)^(srow&3), read seg lkhi^(lrow&3);
// LDS[row][t] = global[row][t^(row&3)] -> read returns global[row][lkhi]:
// bit-identical operands. Epilogue (R9-verified): mins_t only, no atomics.
// ===========================================================================
__global__ __launch_bounds__(512) void vq_gemm(
    const unsigned short* __restrict__ xb, const unsigned short* __restrict__ eb,
    const float* __restrict__ xsq, const float* __restrict__ esq,
    float* __restrict__ mins_t) {
  __shared__ __align__(16) unsigned short As[2][BM * BK];  // 16KB x2
  __shared__ __align__(16) unsigned short Bs[2][BN * BK];  // 16KB x2

  const int tid = threadIdx.x;
  const int wid = tid >> 6;
  const int lane = tid & 63;

  int bidx = blockIdx.x;
  int xcd = bidx & 7;
  int idx = bidx >> 3;
  int nb = xcd * 8 + (idx >> 5);
  int qb = idx & 31;
  const int q0 = qb * BM;
  const int n0 = nb * BN;

  const int wr = wid >> 2, wc = wid & 3;
  const int lrow = lane & 15;
  const int lkhi = lane >> 4;              // 0..3 = K-seg (8 bf16 each)
  const int srow = lane >> 2;              // 0..15: staging row in 16-row stripe
  const int sseg = (lane & 3) ^ (srow & 3);  // swizzled source seg (involution)

  auto stage = [&](int kt, int bf) {
#pragma unroll
    for (int i = 0; i < 2; ++i) {
      int r0 = (wid * 2 + i) * 16;  // multiple of 16 -> row&3 == srow&3
      gl_lds16(xb + (size_t)(q0 + r0 + srow) * C_DIM + kt * BK + sseg * 8,
               (void*)((char*)&As[bf][0] + (size_t)r0 * BK * 2));
      gl_lds16(eb + (size_t)(n0 + r0 + srow) * C_DIM + kt * BK + sseg * 8,
               (void*)((char*)&Bs[bf][0] + (size_t)r0 * BK * 2));
    }
  };

  f32x4 acc[8][4];
#pragma unroll
  for (int i = 0; i < 8; ++i)
#pragma unroll
    for (int j = 0; j < 4; ++j) acc[i][j] = (f32x4){0.f, 0.f, 0.f, 0.f};

  stage(0, 0);
  asm volatile("s_waitcnt vmcnt(0)" ::: "memory");
  __syncthreads();

  const int segA = (lkhi ^ (lrow & 3)) * 8;  // swizzled read seg (elems)
  for (int kt = 0; kt < C_DIM / BK; ++kt) {
    int bf = kt & 1;
    if (kt + 1 < C_DIM / BK) stage(kt + 1, bf ^ 1);
    short8 a[8], b[4];
#pragma unroll
    for (int mi = 0; mi < 8; ++mi)
      a[mi] = *(const short8*)((const char*)&As[bf][0] +
               (size_t)((wr * 128 + mi * 16 + lrow) * BK + segA) * 2);
#pragma unroll
    for (int ni = 0; ni < 4; ++ni)
      b[ni] = *(const short8*)((const char*)&Bs[bf][0] +
               (size_t)((wc * 64 + ni * 16 + lrow) * BK + segA) * 2);
#pragma unroll
    for (int mi = 0; mi < 8; ++mi)
#pragma unroll
      for (int ni = 0; ni < 4; ++ni)
        acc[mi][ni] = __builtin_amdgcn_mfma_f32_16x16x32_bf16(
            a[mi], b[ni], acc[mi][ni], 0, 0, 0);
    asm volatile("s_waitcnt vmcnt(0)" ::: "memory");
    __syncthreads();
  }

  float eqv[4];
#pragma unroll
  for (int ni = 0; ni < 4; ++ni) eqv[ni] = esq[n0 + wc * 64 + ni * 16 + lrow];
  const int g = nb * 4 + wc;
#pragma unroll
  for (int mi = 0; mi < 8; ++mi) {
#pragma unroll
    for (int j = 0; j < 4; ++j) {
      int row = q0 + wr * 128 + mi * 16 + lkhi * 4 + j;
      float xq = xsq[row];
      u64 bst = ~0ull;
#pragma unroll
      for (int ni = 0; ni < 4; ++ni) {
        float d = (xq + eqv[ni]) - 2.0f * acc[mi][ni][j];
        int k = n0 + wc * 64 + ni * 16 + lrow;
        u64 p = ((u64)__float_as_uint(d) << 32) | (unsigned)k;
        if (p < bst) bst = p;
      }
#pragma unroll
      for (int m = 1; m <= 8; m <<= 1) {
        u64 o = __shfl_xor(bst, m);
        if (o < bst) bst = o;
      }
      if (lrow == 0)
        mins_t[(size_t)g * N_Q + row] = __uint_as_float((unsigned)(bst >> 32));
    }
  }
}

// ===========================================================================
// thr[q] = min_g mins_t[g][q] + MARGIN (coalesced column-min).
// ===========================================================================
__global__ __launch_bounds__(256) void vq_thr(const float* __restrict__ mins_t,
                                              float* __restrict__ thr) {
  int q = blockIdx.x * 256 + threadIdx.x;
  float m = 3.4e38f;
  for (int g = 0; g < NGRAN; ++g) m = fminf(m, mins_t[(size_t)g * N_Q + q]);
  thr[q] = m + MARGIN;
}

// ===========================================================================
// Rescore v4 (R9-verified): flag-scan + exact R1 fmaf chains, 4 queries per
// wave, ct transposed coalesced gathers (or cb-direct). atomicMin -> packed2.
// ===========================================================================
__global__ __launch_bounds__(256) void vq_rescore_s(
    const float* __restrict__ xt, const float* __restrict__ cb,
    const float* __restrict__ ct, const float* __restrict__ xsq,
    const float* __restrict__ esq, const float* __restrict__ mins_t,
    const float* __restrict__ thr, u64* __restrict__ packed2) {
  __shared__ int lcnt;
  __shared__ int lbuf[RQB];
  const int g = blockIdx.x;
  const int tid = threadIdx.x;
  if (tid == 0) lcnt = 0;
  __syncthreads();

  const int qbase = blockIdx.y * RQB;
  for (int c = 0; c < RQB; c += 256) {
    int q = qbase + c + tid;
    if (mins_t[(size_t)g * N_Q + q] <= thr[q]) {
      int pos = atomicAdd(&lcnt, 1);
      lbuf[pos] = q;
    }
  }
  __syncthreads();

  const int n = lcnt;
  const int w = tid >> 6;
  const int l = tid & 63;
  const int k = g * GRAN + l;
  const float eq = esq[k];

  for (int i0 = w * 4; i0 < n; i0 += 16) {
    int qi[4];
#pragma unroll
    for (int j = 0; j < 4; ++j) {
      int ii = i0 + j;
      qi[j] = lbuf[ii < n ? ii : n - 1];  // clamp: dup work, same result
    }
    const float4* x0 = (const float4*)(xt + (size_t)qi[0] * C_DIM);
    const float4* x1 = (const float4*)(xt + (size_t)qi[1] * C_DIM);
    const float4* x2 = (const float4*)(xt + (size_t)qi[2] * C_DIM);
    const float4* x3 = (const float4*)(xt + (size_t)qi[3] * C_DIM);
    float a0 = 0.f, a1 = 0.f, a2 = 0.f, a3 = 0.f;
    if (ct) {
      const float* ec = ct + k;  // ct[c][k] = ec[c*N_K]
#pragma unroll 4
      for (int c4 = 0; c4 < 64; ++c4) {
        float e0 = ec[(size_t)(c4 * 4 + 0) * N_K];  // coalesced over lanes
        float e1 = ec[(size_t)(c4 * 4 + 1) * N_K];
        float e2 = ec[(size_t)(c4 * 4 + 2) * N_K];
        float e3 = ec[(size_t)(c4 * 4 + 3) * N_K];
        float4 v0 = x0[c4], v1 = x1[c4], v2 = x2[c4], v3 = x3[c4];
        a0 = fmaf(v0.x, e0, a0); a0 = fmaf(v0.y, e1, a0);
        a0 = fmaf(v0.z, e2, a0); a0 = fmaf(v0.w, e3, a0);
        a1 = fmaf(v1.x, e0, a1); a1 = fmaf(v1.y, e1, a1);
        a1 = fmaf(v1.z, e2, a1); a1 = fmaf(v1.w, e3, a1);
        a2 = fmaf(v2.x, e0, a2); a2 = fmaf(v2.y, e1, a2);
        a2 = fmaf(v2.z, e2, a2); a2 = fmaf(v2.w, e3, a2);
        a3 = fmaf(v3.x, e0, a3); a3 = fmaf(v3.y, e1, a3);
        a3 = fmaf(v3.z, e2, a3); a3 = fmaf(v3.w, e3, a3);
      }
    } else {
      const float4* erow = (const float4*)(cb + (size_t)k * C_DIM);
#pragma unroll 4
      for (int c4 = 0; c4 < 64; ++c4) {
        float4 e = erow[c4];
        float4 v0 = x0[c4], v1 = x1[c4], v2 = x2[c4], v3 = x3[c4];
        a0 = fmaf(v0.x, e.x, a0); a0 = fmaf(v0.y, e.y, a0);
        a0 = fmaf(v0.z, e.z, a0); a0 = fmaf(v0.w, e.w, a0);
        a1 = fmaf(v1.x, e.x, a1); a1 = fmaf(v1.y, e.y, a1);
        a1 = fmaf(v1.z, e.z, a1); a1 = fmaf(v1.w, e.w, a1);
        a2 = fmaf(v2.x, e.x, a2); a2 = fmaf(v2.y, e.y, a2);
        a2 = fmaf(v2.z, e.z, a2); a2 = fmaf(v2.w, e.w, a2);
        a3 = fmaf(v3.x, e.x, a3); a3 = fmaf(v3.y, e.y, a3);
        a3 = fmaf(v3.z, e.z, a3); a3 = fmaf(v3.w, e.w, a3);
      }
    }
    float dv[4] = {a0, a1, a2, a3};
#pragma unroll
    for (int j = 0; j < 4; ++j) {
      float d = (xsq[qi[j]] + eq) - 2.0f * dv[j];
      u64 p = ((u64)__float_as_uint(d) << 32) | (unsigned)k;
#pragma unroll
      for (int s = 1; s <= 32; s <<= 1) {
        u64 o = __shfl_xor(p, s);
        if (o < p) p = o;
      }
      if (l == 0) atomicMin(&packed2[qi[j]], p);
    }
  }
}

__global__ __launch_bounds__(256) void vq_out(const u64* __restrict__ packed2,
                                              int* __restrict__ out) {
  int n = blockIdx.x * 256 + threadIdx.x;
  if (n < N_Q) out[n] = (int)(unsigned)(packed2[n] & 0xffffffffull);
}

// ===========================================================================
// Fallback (R1, known-pass) if ws too small.
// ===========================================================================
#define TQ 64
#define TK 64
#define R1_NCH 8
#define R1_KCHUNK (N_K / R1_NCH)

__global__ __launch_bounds__(256) void r1_esq(const float* __restrict__ cb,
                                              float* __restrict__ esq) {
  int k = blockIdx.x * blockDim.x + threadIdx.x;
  if (k >= N_K) return;
  const float4* row = reinterpret_cast<const float4*>(cb + (size_t)k * C_DIM);
  float s = 0.f;
#pragma unroll 8
  for (int c4 = 0; c4 < C_DIM / 4; ++c4) {
    float4 v = row[c4];
    s = fmaf(v.x, v.x, s); s = fmaf(v.y, v.y, s);
    s = fmaf(v.z, v.z, s); s = fmaf(v.w, v.w, s);
  }
  esq[k] = s;
}

__global__ __launch_bounds__(256) void r1_main(
    const float* __restrict__ hidden, const float* __restrict__ cb,
    const float* __restrict__ esq, float* __restrict__ ws_d,
    int* __restrict__ ws_k) {
  __shared__ __align__(16) float xs[C_DIM][TQ + 4];
  __shared__ __align__(16) float es[TK][C_DIM + 4];
  __shared__ float xsq_part[4][TQ];
  __shared__ float xsq[TQ];
  __shared__ float red_d[16][TQ];
  __shared__ int red_k[16][TQ];
  const int tid = threadIdx.x;
  const int q0 = blockIdx.x * TQ;
  const int b = q0 >> 10;
  const int hw0 = q0 & 1023;
  const float* hb = hidden + (size_t)b * (C_DIM * 1024) + hw0;
  for (int idx = tid; idx < C_DIM * TQ; idx += 256) {
    int c = idx >> 6, q = idx & 63;
    xs[c][q] = hb[c * 1024 + q];
  }
  __syncthreads();
  {
    int q = tid & 63, part = tid >> 6, cbase = part * 64;
    float s = 0.f;
    for (int c = 0; c < 64; ++c) { float v = xs[cbase + c][q]; s = fmaf(v, v, s); }
    xsq_part[part][q] = s;
  }
  __syncthreads();
  if (tid < TQ)
    xsq[tid] = ((xsq_part[0][tid] + xsq_part[1][tid]) + xsq_part[2][tid]) + xsq_part[3][tid];
  __syncthreads();
  const int qt = tid & 15, kt = tid >> 4;
  float xsq_r[4];
#pragma unroll
  for (int i = 0; i < 4; ++i) xsq_r[i] = xsq[qt * 4 + i];
  float bd[4]; int bk[4];
#pragma unroll
  for (int i = 0; i < 4; ++i) { bd[i] = 3.4e38f; bk[i] = 0x7fffffff; }
  const int kbegin = blockIdx.y * R1_KCHUNK;
  for (int kt0 = kbegin; kt0 < kbegin + R1_KCHUNK; kt0 += TK) {
    __syncthreads();
    for (int idx = tid; idx < TK * (C_DIM / 4); idx += 256) {
      int kk = idx >> 6, c4 = idx & 63;
      float4 v = reinterpret_cast<const float4*>(cb + (size_t)(kt0 + kk) * C_DIM)[c4];
      es[kk][c4 * 4 + 0] = v.x; es[kk][c4 * 4 + 1] = v.y;
      es[kk][c4 * 4 + 2] = v.z; es[kk][c4 * 4 + 3] = v.w;
    }
    __syncthreads();
    float acc[4][4];
#pragma unroll
    for (int i = 0; i < 4; ++i)
#pragma unroll
      for (int j = 0; j < 4; ++j) acc[i][j] = 0.f;
    for (int c4 = 0; c4 < C_DIM; c4 += 4) {
      float4 xv0 = *reinterpret_cast<const float4*>(&xs[c4 + 0][qt * 4]);
      float4 xv1 = *reinterpret_cast<const float4*>(&xs[c4 + 1][qt * 4]);
      float4 xv2 = *reinterpret_cast<const float4*>(&xs[c4 + 2][qt * 4]);
      float4 xv3 = *reinterpret_cast<const float4*>(&xs[c4 + 3][qt * 4]);
      float xq0[4] = {xv0.x, xv0.y, xv0.z, xv0.w};
      float xq1[4] = {xv1.x, xv1.y, xv1.z, xv1.w};
      float xq2[4] = {xv2.x, xv2.y, xv2.z, xv2.w};
      float xq3[4] = {xv3.x, xv3.y, xv3.z, xv3.w};
      float4 ev[4];
#pragma unroll
      for (int j = 0; j < 4; ++j)
        ev[j] = *reinterpret_cast<const float4*>(&es[kt * 4 + j][c4]);
#pragma unroll
      for (int i = 0; i < 4; ++i) {
#pragma unroll
        for (int j = 0; j < 4; ++j) {
          float a = acc[i][j];
          a = fmaf(xq0[i], ev[j].x, a);
          a = fmaf(xq1[i], ev[j].y, a);
          a = fmaf(xq2[i], ev[j].z, a);
          a = fmaf(xq3[i], ev[j].w, a);
          acc[i][j] = a;
        }
      }
    }
#pragma unroll
    for (int j = 0; j < 4; ++j) {
      int k = kt0 + kt * 4 + j;
      float eq = esq[k];
#pragma unroll
      for (int i = 0; i < 4; ++i) {
        float t1 = xsq_r[i] + eq;
        float d = t1 - 2.0f * acc[i][j];
        if (d < bd[i]) { bd[i] = d; bk[i] = k; }
      }
    }
  }
#pragma unroll
  for (int i = 0; i < 4; ++i) {
    red_d[kt][qt * 4 + i] = bd[i];
    red_k[kt][qt * 4 + i] = bk[i];
  }
  __syncthreads();
  if (tid < TQ) {
    float d = red_d[0][tid]; int kb = red_k[0][tid];
    for (int t = 1; t < 16; ++t) {
      float dn = red_d[t][tid]; int kn = red_k[t][tid];
      if (dn < d || (dn == d && kn < kb)) { d = dn; kb = kn; }
    }
    int q = q0 + tid;
    ws_d[(size_t)q * R1_NCH + blockIdx.y] = d;
    ws_k[(size_t)q * R1_NCH + blockIdx.y] = kb;
  }
}

__global__ __launch_bounds__(256) void r1_final(
    const float* __restrict__ ws_d, const int* __restrict__ ws_k,
    int* __restrict__ out) {
  int n = blockIdx.x * blockDim.x + threadIdx.x;
  if (n >= N_Q) return;
  const float* dp = ws_d + (size_t)n * R1_NCH;
  const int* kp = ws_k + (size_t)n * R1_NCH;
  float d = dp[0]; int kb = kp[0];
#pragma unroll
  for (int j = 1; j < R1_NCH; ++j) {
    float dn = dp[j]; int kn = kp[j];
    if (dn < d || (dn == d && kn < kb)) { d = dn; kb = kn; }
  }
  out[n] = kb;
}

extern "C" void kernel_launch(void* const* d_in, const int* in_sizes, int n_in,
                              void* d_out, int out_size, void* d_ws,
                              size_t ws_size, hipStream_t stream) {
  const float* hidden = (const float*)d_in[0];
  const float* cb = (const float*)d_in[1];
  int* out = (int*)d_out;

  const size_t MB = 1024 * 1024;
  const size_t NEED_FULL = 45 * MB;   // with transposed codebook ct
  const size_t NEED_MID = 29 * MB;    // without ct

  if (ws_size >= NEED_MID) {
    const bool full = ws_size >= NEED_FULL;
    char* w = (char*)d_ws;
    unsigned short* xb = (unsigned short*)(w);                 // 4MB
    unsigned short* eb = (unsigned short*)(w + 4 * MB);        // 8MB
    float* xt = (float*)(w + 12 * MB);                         // 8MB
    float* ct = full ? (float*)(w + 20 * MB) : nullptr;        // 16MB
    float* mins_t = (float*)(w + (full ? 36 : 20) * MB);       // 8MB [g][q]
    char* s = w + (full ? 44 : 28) * MB;
    float* xsq = (float*)(s);                                  // 32KB
    float* esq = (float*)(s + 65536);                          // 64KB
    float* thr = (float*)(s + 131072);                         // 32KB
    u64* packed2 = (u64*)(s + 196608);                         // 64KB

    vq_pre_x<<<dim3(256), dim3(256), 0, stream>>>(hidden, xt, xb, xsq, packed2);
    vq_pre_e<<<dim3(N_K / 64), dim3(256), 0, stream>>>(cb, eb, esq, ct);
    vq_gemm<<<dim3((N_Q / BM) * (N_K / BN)), dim3(512), 0, stream>>>(
        xb, eb, xsq, esq, mins_t);
    vq_thr<<<dim3(N_Q / 256), dim3(256), 0, stream>>>(mins_t, thr);
    vq_rescore_s<<<dim3(NGRAN, RQS), dim3(256), 0, stream>>>(
        xt, cb, ct, xsq, esq, mins_t, thr, packed2);
    vq_out<<<dim3(N_Q / 256), dim3(256), 0, stream>>>(packed2, out);
  } else {
    float* esq_f = (float*)d_ws;
    float* ws_d = (float*)((char*)d_ws + 65536);
    int* ws_k = (int*)((char*)d_ws + 65536 + N_Q * R1_NCH * 4);
    r1_esq<<<dim3(N_K / 256), dim3(256), 0, stream>>>(cb, esq_f);
    r1_main<<<dim3(N_Q / TQ, R1_NCH), dim3(256), 0, stream>>>(hidden, cb, esq_f, ws_d, ws_k);
    r1_final<<<dim3(N_Q / 256), dim3(256), 0, stream>>>(ws_d, ws_k, out);
  }
}